// Round 6
// baseline (207.326 us; speedup 1.0000x reference)
//
#include <hip/hip_runtime.h>
#include <math.h>

#define B_SZ 4096
#define N_PTS 2048
#define BLOCK 256

// 16-byte vector type usable with __builtin_nontemporal_load
typedef float f4 __attribute__((ext_vector_type(4)));

// ws float layout:
//   WS_PC  : per-element per-wave pc partials {pp,pp2,t,t2} : 4096*4 f4
//   WS_XD  : per-element per-wave xd partials               : 4096*4 floats
//   WS_TOT : per-element totals                             : 4096 floats
#define WS_PC   0
#define WS_XD   65536
#define WS_TOT  (65536 + 16384)

__device__ __forceinline__ float huber1(float a) {
    // a >= 0, delta = 1: 0.5*q*q + (a - q), q = min(a,1)
    float q = fminf(a, 1.0f);
    return 0.5f * q * q + (a - q);
}

// ---------------------------------------------------------------------------
// R6 rationale: R5's NT loads were the first real win (224->207 us; sweep
// 61.5 -> <=~45 us) — the read wall was cache-allocation dwell. Next term:
// outstanding-load DEPTH. R5 serialized per element (6 loads -> reduce ->
// store -> next element). Here ALL loads for both owned elements (12 xd /
// 8 pc NT loads) are issued before any consumption; per-element private
// accumulation; interleaved independent shuffle-reduce chains at the end.
// launch_bounds(256,6) raises VGPR cap to ~85 so the burst fits (6 blocks/CU
// instead of 8 — depth compensates). Pre-NT this was null (R2) but the
// regime changed: re-test per the regime-gate rule.
// ---------------------------------------------------------------------------
__global__ __launch_bounds__(BLOCK, 6) void sweep(
    const float* __restrict__ point_cloud,      // (B,3,N)
    const float* __restrict__ x_delta,          // (B,3,N)
    const float* __restrict__ center_label,     // (B,3)
    float* __restrict__ ws)
{
    const int tid  = threadIdx.x;
    const int wave = tid >> 6;
    const int lane = tid & 63;

    if (blockIdx.x < (B_SZ / 2)) {
        // ---- x_delta: block owns elements {2s, 2s+1}, 1536 f4 each ----
        const int s = blockIdx.x;
        const int e0 = 2 * s;
        const f4* p0 = (const f4*)x_delta + (size_t)e0 * 1536;
        const f4* p1 = p0 + 1536;

        // 12 NT loads in flight before ANY consumption (48 dest VGPRs)
        f4 d[12];
        #pragma unroll
        for (int k = 0; k < 6; ++k)
            d[k] = __builtin_nontemporal_load(p0 + k * BLOCK + tid);
        #pragma unroll
        for (int k = 0; k < 6; ++k)
            d[6 + k] = __builtin_nontemporal_load(p1 + k * BLOCK + tid);

        float v0 = 0.f, v1 = 0.f;
        #pragma unroll
        for (int k = 0; k < 6; ++k)
            v0 += d[k][0]*d[k][0] + d[k][1]*d[k][1] + d[k][2]*d[k][2] + d[k][3]*d[k][3];
        #pragma unroll
        for (int k = 6; k < 12; ++k)
            v1 += d[k][0]*d[k][0] + d[k][1]*d[k][1] + d[k][2]*d[k][2] + d[k][3]*d[k][3];

        // two independent reduce chains, interleaved for ILP
        #pragma unroll
        for (int off = 32; off > 0; off >>= 1) {
            v0 += __shfl_down(v0, off, 64);
            v1 += __shfl_down(v1, off, 64);
        }
        if (lane == 0) {
            ws[WS_XD + (e0    ) * 4 + wave] = v0;
            ws[WS_XD + (e0 + 1) * 4 + wave] = v1;
        }
    } else {
        // ---- point-cloud rows 0/1: block owns elements {2s, 2s+1} ----
        const int s = blockIdx.x - (B_SZ / 2);
        const int e0 = 2 * s;
        const f4* pc4 = (const f4*)point_cloud;
        f4* __restrict__ wpc = (f4*)(ws + WS_PC);

        const f4* pxa = pc4 + (size_t)e0 * 1536;        // e0 x row: 512 f4
        const f4* pxb = pxa + 1536;                     // e1 x row

        // 8 NT loads in flight before ANY consumption (32 dest VGPRs)
        const f4 xa0 = __builtin_nontemporal_load(pxa + tid);
        const f4 xa1 = __builtin_nontemporal_load(pxa + BLOCK + tid);
        const f4 ya0 = __builtin_nontemporal_load(pxa + 512 + tid);
        const f4 ya1 = __builtin_nontemporal_load(pxa + 512 + BLOCK + tid);
        const f4 xb0 = __builtin_nontemporal_load(pxb + tid);
        const f4 xb1 = __builtin_nontemporal_load(pxb + BLOCK + tid);
        const f4 yb0 = __builtin_nontemporal_load(pxb + 512 + tid);
        const f4 yb1 = __builtin_nontemporal_load(pxb + 512 + BLOCK + tid);

        // block-uniform scalars (scalar-path loads)
        const float cxa = center_label[e0 * 3 + 0];
        const float cya = center_label[e0 * 3 + 1];
        const float vna  = sqrtf(cxa * cxa + cya * cya);
        const float pdxa = -cya / vna, pdya = cxa / vna;
        const float cxb = center_label[(e0 + 1) * 3 + 0];
        const float cyb = center_label[(e0 + 1) * 3 + 1];
        const float vnb  = sqrtf(cxb * cxb + cyb * cyb);
        const float pdxb = -cyb / vnb, pdyb = cxb / vnb;

        float sa_pp = 0.f, sa_pp2 = 0.f, sa_t = 0.f, sa_t2 = 0.f;
        float sb_pp = 0.f, sb_pp2 = 0.f, sb_t = 0.f, sb_t2 = 0.f;
        {
            const float xsa[8] = {xa0[0],xa0[1],xa0[2],xa0[3], xa1[0],xa1[1],xa1[2],xa1[3]};
            const float ysa[8] = {ya0[0],ya0[1],ya0[2],ya0[3], ya1[0],ya1[1],ya1[2],ya1[3]};
            const float xsb[8] = {xb0[0],xb0[1],xb0[2],xb0[3], xb1[0],xb1[1],xb1[2],xb1[3]};
            const float ysb[8] = {yb0[0],yb0[1],yb0[2],yb0[3], yb1[0],yb1[1],yb1[2],yb1[3]};
            #pragma unroll
            for (int j = 0; j < 8; ++j) {
                const float ppa = xsa[j] * pdxa + ysa[j] * pdya;
                const float ta  = xsa[j] * cxa  + ysa[j] * cya;
                sa_pp += ppa; sa_pp2 += ppa * ppa; sa_t += ta; sa_t2 += ta * ta;
                const float ppb = xsb[j] * pdxb + ysb[j] * pdyb;
                const float tb  = xsb[j] * cxb  + ysb[j] * cyb;
                sb_pp += ppb; sb_pp2 += ppb * ppb; sb_t += tb; sb_t2 += tb * tb;
            }
        }
        // 8 independent reduce chains, interleaved
        #pragma unroll
        for (int off = 32; off > 0; off >>= 1) {
            sa_pp  += __shfl_down(sa_pp,  off, 64);
            sb_pp  += __shfl_down(sb_pp,  off, 64);
            sa_pp2 += __shfl_down(sa_pp2, off, 64);
            sb_pp2 += __shfl_down(sb_pp2, off, 64);
            sa_t   += __shfl_down(sa_t,   off, 64);
            sb_t   += __shfl_down(sb_t,   off, 64);
            sa_t2  += __shfl_down(sa_t2,  off, 64);
            sb_t2  += __shfl_down(sb_t2,  off, 64);
        }
        if (lane == 0) {
            f4 ra; ra[0] = sa_pp; ra[1] = sa_pp2; ra[2] = sa_t; ra[3] = sa_t2;
            f4 rb; rb[0] = sb_pp; rb[1] = sb_pp2; rb[2] = sb_t; rb[3] = sb_t2;
            wpc[(e0    ) * 4 + wave] = ra;
            wpc[(e0 + 1) * 4 + wave] = rb;
        }
    }
}

// Finalize: one thread per element. Gathers 4 pc f4-partials + 4 xd floats,
// runs the (verified) label epilogue, writes per-element total. Stateless.
__global__ __launch_bounds__(BLOCK) void finalize(
    const float* __restrict__ mask_xyz_mean,    // (B,3)
    const float* __restrict__ center_label,     // (B,3)
    const float* __restrict__ size_residual,    // (B,3)
    const float* __restrict__ heading_residual, // (B,)
    const float* __restrict__ mean_sizes,       // (8,3)
    const int*   __restrict__ size_class,       // (B,)
    const int*   __restrict__ heading_class,    // (B,)
    float* __restrict__ ws)
{
    const int e = blockIdx.x * BLOCK + threadIdx.x;   // [0, 4096)

    float s_pp = 0.f, s_pp2 = 0.f, s_t = 0.f, s_t2 = 0.f;
    const f4* pcp = ((const f4*)(ws + WS_PC)) + (size_t)e * 4;
    #pragma unroll
    for (int i = 0; i < 4; ++i) {
        const f4 p = pcp[i];
        s_pp += p[0]; s_pp2 += p[1]; s_t += p[2]; s_t2 += p[3];
    }
    float s_d2 = 0.f;
    #pragma unroll
    for (int i = 0; i < 4; ++i) s_d2 += ws[WS_XD + e * 4 + i];

    // --- label-side scalar math (identical to verified R2/R3/R5 epilogue) ---
    const float cx = center_label[e * 3 + 0];
    const float cy = center_label[e * 3 + 1];
    const float cz = center_label[e * 3 + 2];
    const float vnorm2 = cx * cx + cy * cy;
    const float vnorm  = sqrtf(vnorm2);
    const float pdx = -cy / vnorm;
    const float pdy =  cx / vnorm;

    const float mx = mask_xyz_mean[e * 3 + 0];
    const float my = mask_xyz_mean[e * 3 + 1];
    const float mz = mask_xyz_mean[e * 3 + 2];
    const float dxc = mx - cx, dyc = my - cy, dzc = mz - cz;
    const float center_dist = sqrtf(dxc * dxc + dyc * dyc + dzc * dzc);

    const int sc = size_class[e];
    const float l  = mean_sizes[sc * 3 + 0] + size_residual[e * 3 + 0];
    const float w_ = mean_sizes[sc * 3 + 1] + size_residual[e * 3 + 1];
    // h (size z) does not affect the 2D corners used below

    const float theta = heading_residual[e] +
                        (float)heading_class[e] * (float)(M_PI / 12.0);
    const float c = cosf(theta);
    const float s = sinf(theta);
    const float hl = 0.5f * l, hw = 0.5f * w_;

    // bottom corners k=4..7: sx={1,1,-1,-1}, sy={1,-1,-1,1}
    float X[4], Y[4];
    X[0] =  c * hl - s * hw + cx;  Y[0] =  s * hl + c * hw + cy;
    X[1] =  c * hl + s * hw + cx;  Y[1] =  s * hl - c * hw + cy;
    X[2] = -c * hl + s * hw + cx;  Y[2] = -s * hl - c * hw + cy;
    X[3] = -c * hl - s * hw + cx;  Y[3] = -s * hl + c * hw + cy;

    float ppmax = -INFINITY, ppmin = INFINITY;
    float pmax  = -INFINITY, pmin  = INFINITY;
    #pragma unroll
    for (int k = 0; k < 4; ++k) {
        const float pp = X[k] * pdx + Y[k] * pdy;
        const float pj = (X[k] * cx + Y[k] * cy) / vnorm;
        ppmax = fmaxf(ppmax, pp); ppmin = fminf(ppmin, pp);
        pmax  = fmaxf(pmax,  pj); pmin  = fminf(pmin,  pj);
    }
    const float std_y_label  = (ppmax - ppmin) * 0.25f;
    const float mean_y_label = (ppmax + ppmin) * 0.5f;
    const float std_label    = (pmax - pmin) * 0.25f;
    const float mean_label   = (pmax + pmin) * 0.5f;

    // --- point-cloud stats (ddof=1) ---
    const float invN   = 1.0f / (float)N_PTS;
    const float invNm1 = 1.0f / (float)(N_PTS - 1);

    const float mean_y_pc = s_pp * invN;
    const float var_y = (s_pp2 - s_pp * s_pp * invN) * invNm1;
    const float std_y_pc = sqrtf(fmaxf(var_y, 0.0f));

    const float mean_pc = (s_t * invN) / vnorm;
    const float var_x = ((s_t2 - s_t * s_t * invN) * invNm1) / vnorm2;
    const float std_pc = sqrtf(fmaxf(var_x, 0.0f));

    const float delta_norm = sqrtf(s_d2);

    const float total =
          0.5f  * huber1(center_dist)
        +         huber1(fabsf(std_label  - std_pc))
        +         huber1(fabsf(mean_label - mean_pc))
        + 0.01f * huber1(delta_norm)
        +         huber1(fabsf(mean_y_label - mean_y_pc))
        +         huber1(fabsf(std_y_label  - std_y_pc));

    ws[WS_TOT + e] = total;
}

// Final reduce: single block sums the 4096 per-element totals (fixed order).
__global__ __launch_bounds__(BLOCK) void loss_reduce(
    const float* __restrict__ ws, float* __restrict__ out)
{
    const int tid = threadIdx.x;
    const float4* w4 = (const float4*)(ws + WS_TOT);   // 1024 float4

    float s = 0.f;
    #pragma unroll
    for (int k = 0; k < B_SZ / 4 / BLOCK; ++k) {
        const float4 v = w4[tid + k * BLOCK];
        s += v.x + v.y + v.z + v.w;
    }

    #pragma unroll
    for (int off = 32; off > 0; off >>= 1)
        s += __shfl_down(s, off, 64);

    __shared__ float red[BLOCK / 64];
    const int wave = tid >> 6;
    const int lane = tid & 63;
    if (lane == 0) red[wave] = s;
    __syncthreads();

    if (tid == 0) {
        #pragma unroll
        for (int w = 1; w < BLOCK / 64; ++w) s += red[w];
        out[0] = s * (0.4f / (float)B_SZ);
    }
}

extern "C" void kernel_launch(void* const* d_in, const int* in_sizes, int n_in,
                              void* d_out, int out_size, void* d_ws, size_t ws_size,
                              hipStream_t stream) {
    const float* mask_xyz_mean    = (const float*)d_in[0];
    const float* point_cloud      = (const float*)d_in[1];
    const float* x_delta          = (const float*)d_in[2];
    const float* center_label     = (const float*)d_in[3];
    const float* size_residual    = (const float*)d_in[4];
    const float* heading_residual = (const float*)d_in[5];
    const float* mean_sizes       = (const float*)d_in[6];
    const int*   size_class       = (const int*)d_in[7];
    const int*   heading_class    = (const int*)d_in[8];
    float* ws  = (float*)d_ws;    // ~340 KB used
    float* out = (float*)d_out;

    // blocks 0..2047: x_delta (element pairs); 2048..4095: point-cloud pairs
    sweep<<<B_SZ, BLOCK, 0, stream>>>(point_cloud, x_delta, center_label, ws);
    finalize<<<B_SZ / BLOCK, BLOCK, 0, stream>>>(
        mask_xyz_mean, center_label, size_residual, heading_residual,
        mean_sizes, size_class, heading_class, ws);
    loss_reduce<<<1, BLOCK, 0, stream>>>(ws, out);
}